// Round 5
// baseline (2756.993 us; speedup 1.0000x reference)
//
#include <hip/hip_runtime.h>
#include <hip/hip_bf16.h>

// LlamaMLPInfer: SwiGLU MLP with group(128)-dequantized int4 weights.
// R5: m201-style phased K-loop (T3+T4+T5) for both GEMMs.
//  gateup: 4 phases/K-tile {g-ks0, u-ks0, g-ks1, u-ks1}, 16 MFMA each;
//  down:   2 phases/K-tile. Staging for t+1 issued at tile head; single
//  late vmcnt(0) before dequant+ds_write at tile tail; raw s_barrier
//  (no vmcnt drain at barriers); T1 XCD-chunked swizzle; T2 LDS swizzle.

#define HDIM 4096
#define IDIM 14336
#define MTOK 4096
#define GRP 128

typedef __attribute__((ext_vector_type(8))) short bf16x8;
typedef __attribute__((ext_vector_type(4))) float f32x4;
typedef __attribute__((ext_vector_type(4))) unsigned short u16x4;

#define WAIT_LGKM0 asm volatile("s_waitcnt lgkmcnt(0)" ::: "memory")
#define WAIT_VM0   asm volatile("s_waitcnt vmcnt(0)" ::: "memory")
#define SBAR       __builtin_amdgcn_s_barrier()
#define SCHB       __builtin_amdgcn_sched_barrier(0)

__device__ __forceinline__ unsigned short f2bf(float f) {
  union { float f; unsigned int u; } v; v.f = f;
  return (unsigned short)((v.u + 0x7fffu + ((v.u >> 16) & 1u)) >> 16);  // RNE
}
// pack two f32 -> two bf16 (truncate): low16 = bf16(a), high16 = bf16(b)
__device__ __forceinline__ unsigned pk2(float a, float b) {
  union { float f; unsigned u; } ua, ub; ua.f = a; ub.f = b;
  return __builtin_amdgcn_perm(ub.u, ua.u, 0x07060302u);
}

// ---------------- x fp32 -> bf16 ----------------
__global__ __launch_bounds__(256) void cvt_x_kernel(const float* __restrict__ x,
                                                    unsigned short* __restrict__ xb) {
  const int n = MTOK * HDIM;
  const int stride = gridDim.x * 256 * 4;
  for (int i = (blockIdx.x * 256 + threadIdx.x) * 4; i < n; i += stride) {
    float4 v = *reinterpret_cast<const float4*>(x + i);
    u16x4 o;
    o[0] = f2bf(v.x); o[1] = f2bf(v.y); o[2] = f2bf(v.z); o[3] = f2bf(v.w);
    *reinterpret_cast<u16x4*>(xb + i) = o;
  }
}

// ================= fused gate+up GEMM =================
// 256x128 tile, BK=64, 512 thr (8 waves, 4Mx2N).
__global__ __launch_bounds__(512, 2) void gateup_kernel(
    const unsigned short* __restrict__ xb,
    const int* __restrict__ gq, const float* __restrict__ gs,
    const int* __restrict__ uq, const float* __restrict__ us,
    unsigned short* __restrict__ inter)
{
  __shared__ unsigned short As[2 * 256 * 64];  // 64 KB dbuf
  __shared__ unsigned short Bg[2 * 128 * 64];  // 32 KB dbuf
  __shared__ unsigned short Bu[2 * 128 * 64];  // 32 KB dbuf

  const int tid  = threadIdx.x;
  const int lane = tid & 63;
  const int wid  = tid >> 6;
  const int wm   = wid >> 1, wn = wid & 1;
  // XCD-chunked swizzle: 1792 blocks, 8 XCDs, 224 contiguous logicals/XCD.
  const int p  = blockIdx.x;
  const int l  = (p & 7) * 224 + (p >> 3);
  const int m0 = (l & 15) * 256;
  const int n0 = (l >> 4) * 128;
  const int lr = lane & 15, lc = lane >> 4;

  // A staging (global_load_lds, linear dest, pre-swizzled source col)
  const int ra   = tid >> 3;
  const int scol = ((tid & 7) ^ (ra & 7)) << 3;
  const unsigned short* pa = xb + (long)(m0 + ra) * HDIM + scol;
  unsigned short* lbase = (unsigned short*)As + wid * 512;

  // B staging (reg-staged, swizzled ds_write)
  const int rb  = tid >> 3;
  const int cb  = (tid & 7) << 3;
  const int swz = ((tid & 7) ^ (rb & 7)) << 3;
  const int sidx0 = rb * 64 + swz;
  const int sidx1 = (64 + rb) * 64 + swz;
  const int*   pg0 = gq + (long)(n0 + rb) * HDIM + cb;
  const int*   pg1 = pg0 + 64 * HDIM;
  const int*   pu0 = uq + (long)(n0 + rb) * HDIM + cb;
  const int*   pu1 = pu0 + 64 * HDIM;
  const float* psg0 = gs + (n0 + rb) * (HDIM / GRP);
  const float* psg1 = psg0 + 64 * (HDIM / GRP);
  const float* psu0 = us + (n0 + rb) * (HDIM / GRP);
  const float* psu1 = psu0 + 64 * (HDIM / GRP);

  int4 q[8];
  float sc[4];

#define GU_ISSUEA(KTA, WRP) do {                                              \
    const unsigned short* g_ = pa + (KTA) * 64;                               \
    unsigned short* l_ = lbase + (WRP) * 16384;                               \
    _Pragma("unroll")                                                         \
    for (int it = 0; it < 4; ++it)                                            \
      __builtin_amdgcn_global_load_lds(                                       \
          (const __attribute__((address_space(1))) unsigned int*)(g_ + it * 64 * HDIM), \
          (__attribute__((address_space(3))) unsigned int*)(l_ + it * 4096), 16, 0, 0); \
  } while (0)

#define GU_LOADB(KT) do { const int kk_ = (KT) << 6;                          \
    q[0] = *(const int4*)(pg0 + kk_); q[1] = *(const int4*)(pg0 + kk_ + 4);   \
    q[2] = *(const int4*)(pg1 + kk_); q[3] = *(const int4*)(pg1 + kk_ + 4);   \
    q[4] = *(const int4*)(pu0 + kk_); q[5] = *(const int4*)(pu0 + kk_ + 4);   \
    q[6] = *(const int4*)(pu1 + kk_); q[7] = *(const int4*)(pu1 + kk_ + 4);   \
    const int so_ = (KT) >> 1;                                                \
    sc[0] = psg0[so_]; sc[1] = psg1[so_]; sc[2] = psu0[so_]; sc[3] = psu1[so_]; \
  } while (0)

#define GU_WRITEB(WRP) do {                                                   \
    unsigned short* Bg_ = (unsigned short*)Bg + (WRP) * 8192;                 \
    unsigned short* Bu_ = (unsigned short*)Bu + (WRP) * 8192;                 \
    uint4 w_;                                                                 \
    w_.x = pk2((float)q[0].x * sc[0], (float)q[0].y * sc[0]);                 \
    w_.y = pk2((float)q[0].z * sc[0], (float)q[0].w * sc[0]);                 \
    w_.z = pk2((float)q[1].x * sc[0], (float)q[1].y * sc[0]);                 \
    w_.w = pk2((float)q[1].z * sc[0], (float)q[1].w * sc[0]);                 \
    *(uint4*)&Bg_[sidx0] = w_;                                                \
    w_.x = pk2((float)q[2].x * sc[1], (float)q[2].y * sc[1]);                 \
    w_.y = pk2((float)q[2].z * sc[1], (float)q[2].w * sc[1]);                 \
    w_.z = pk2((float)q[3].x * sc[1], (float)q[3].y * sc[1]);                 \
    w_.w = pk2((float)q[3].z * sc[1], (float)q[3].w * sc[1]);                 \
    *(uint4*)&Bg_[sidx1] = w_;                                                \
    w_.x = pk2((float)q[4].x * sc[2], (float)q[4].y * sc[2]);                 \
    w_.y = pk2((float)q[4].z * sc[2], (float)q[4].w * sc[2]);                 \
    w_.z = pk2((float)q[5].x * sc[2], (float)q[5].y * sc[2]);                 \
    w_.w = pk2((float)q[5].z * sc[2], (float)q[5].w * sc[2]);                 \
    *(uint4*)&Bu_[sidx0] = w_;                                                \
    w_.x = pk2((float)q[6].x * sc[3], (float)q[6].y * sc[3]);                 \
    w_.y = pk2((float)q[6].z * sc[3], (float)q[6].w * sc[3]);                 \
    w_.z = pk2((float)q[7].x * sc[3], (float)q[7].y * sc[3]);                 \
    w_.w = pk2((float)q[7].z * sc[3], (float)q[7].w * sc[3]);                 \
    *(uint4*)&Bu_[sidx1] = w_;                                                \
  } while (0)

  f32x4 accg[4][4], accu[4][4];
  const f32x4 zero = {0.f, 0.f, 0.f, 0.f};
#pragma unroll
  for (int i = 0; i < 4; ++i)
#pragma unroll
    for (int j = 0; j < 4; ++j) { accg[i][j] = zero; accu[i][j] = zero; }

  // prologue: tile 0 -> parity 0
  GU_LOADB(0);
  GU_ISSUEA(0, 0);
  GU_WRITEB(0);           // compiler inserts vmcnt wait for q
  WAIT_VM0; WAIT_LGKM0;
  SBAR;
  SCHB;

  const int NK = HDIM / 64;
#pragma unroll 1
  for (int kt = 0; kt < NK; ++kt) {
    const int RD = kt & 1, WR = RD ^ 1;
    const int ktn = (kt + 1 < NK) ? kt + 1 : kt;   // clamped prefetch
    GU_LOADB(ktn);
    GU_ISSUEA(ktn, WR);
    SCHB;
    const unsigned short* Ab  = (const unsigned short*)As + RD * 16384;
    const unsigned short* Bgb = (const unsigned short*)Bg + RD * 8192;
    const unsigned short* Bub = (const unsigned short*)Bu + RD * 8192;
    const int soff0 = (lc ^ (lr & 7)) << 3;
    const int soff1 = ((4 + lc) ^ (lr & 7)) << 3;
    bf16x8 af[4], bfr[4];
    // ---- ph0: g, ks0 ----
#pragma unroll
    for (int mi = 0; mi < 4; ++mi)
      af[mi] = *(const bf16x8*)&Ab[(wm * 64 + mi * 16 + lr) * 64 + soff0];
#pragma unroll
    for (int ni = 0; ni < 4; ++ni)
      bfr[ni] = *(const bf16x8*)&Bgb[(wn * 64 + ni * 16 + lr) * 64 + soff0];
    SBAR; WAIT_LGKM0; SCHB;
    __builtin_amdgcn_s_setprio(1);
#pragma unroll
    for (int ni = 0; ni < 4; ++ni)
#pragma unroll
      for (int mi = 0; mi < 4; ++mi)
        accg[mi][ni] = __builtin_amdgcn_mfma_f32_16x16x32_bf16(af[mi], bfr[ni], accg[mi][ni], 0, 0, 0);
    __builtin_amdgcn_s_setprio(0);
    SBAR;
    // ---- ph1: u, ks0 (af reused) ----
#pragma unroll
    for (int ni = 0; ni < 4; ++ni)
      bfr[ni] = *(const bf16x8*)&Bub[(wn * 64 + ni * 16 + lr) * 64 + soff0];
    SBAR; WAIT_LGKM0; SCHB;
    __builtin_amdgcn_s_setprio(1);
#pragma unroll
    for (int ni = 0; ni < 4; ++ni)
#pragma unroll
      for (int mi = 0; mi < 4; ++mi)
        accu[mi][ni] = __builtin_amdgcn_mfma_f32_16x16x32_bf16(af[mi], bfr[ni], accu[mi][ni], 0, 0, 0);
    __builtin_amdgcn_s_setprio(0);
    SBAR;
    // ---- ph2: g, ks1 ----
#pragma unroll
    for (int mi = 0; mi < 4; ++mi)
      af[mi] = *(const bf16x8*)&Ab[(wm * 64 + mi * 16 + lr) * 64 + soff1];
#pragma unroll
    for (int ni = 0; ni < 4; ++ni)
      bfr[ni] = *(const bf16x8*)&Bgb[(wn * 64 + ni * 16 + lr) * 64 + soff1];
    SBAR; WAIT_LGKM0; SCHB;
    __builtin_amdgcn_s_setprio(1);
#pragma unroll
    for (int ni = 0; ni < 4; ++ni)
#pragma unroll
      for (int mi = 0; mi < 4; ++mi)
        accg[mi][ni] = __builtin_amdgcn_mfma_f32_16x16x32_bf16(af[mi], bfr[ni], accg[mi][ni], 0, 0, 0);
    __builtin_amdgcn_s_setprio(0);
    SBAR;
    // ---- ph3: u, ks1 ----
#pragma unroll
    for (int ni = 0; ni < 4; ++ni)
      bfr[ni] = *(const bf16x8*)&Bub[(wn * 64 + ni * 16 + lr) * 64 + soff1];
    SBAR; WAIT_LGKM0; SCHB;
    __builtin_amdgcn_s_setprio(1);
#pragma unroll
    for (int ni = 0; ni < 4; ++ni)
#pragma unroll
      for (int mi = 0; mi < 4; ++mi)
        accu[mi][ni] = __builtin_amdgcn_mfma_f32_16x16x32_bf16(af[mi], bfr[ni], accu[mi][ni], 0, 0, 0);
    __builtin_amdgcn_s_setprio(0);
    // ---- tile tail: retire staging loads, dequant+write WR ----
    SCHB;
    WAIT_VM0;           // B(t+1)+A(t+1) issued ~4 phases ago -> cheap
    SCHB;
    GU_WRITEB(WR);
    WAIT_LGKM0;
    SBAR;
    SCHB;
  }

  // ---- epilogue: silu(g)*u -> bf16 ----
  const int r0 = m0 + wm * 64, c0 = n0 + wn * 64;
#pragma unroll
  for (int mi = 0; mi < 4; ++mi)
#pragma unroll
    for (int ni = 0; ni < 4; ++ni)
#pragma unroll
      for (int r = 0; r < 4; ++r) {
        float g = accg[mi][ni][r], u = accu[mi][ni][r];
        float sv = g / (1.f + __expf(-g));
        int row = r0 + mi * 16 + lc * 4 + r;
        int col = c0 + ni * 16 + lr;
        inter[(long)row * IDIM + col] = f2bf(sv * u);
      }
#undef GU_ISSUEA
#undef GU_LOADB
#undef GU_WRITEB
}

// ================= down GEMM =================
// 256x128 tile, BK=64, 2 phases/K-tile.
__global__ __launch_bounds__(512, 2) void down_kernel(
    const unsigned short* __restrict__ inter,
    const int* __restrict__ dq, const float* __restrict__ dsc,
    float* __restrict__ out)
{
  __shared__ unsigned short As[2 * 256 * 64];  // 64 KB dbuf
  __shared__ unsigned short Bs[2 * 128 * 64];  // 32 KB dbuf

  const int tid  = threadIdx.x;
  const int lane = tid & 63;
  const int wid  = tid >> 6;
  const int wm   = wid >> 1, wn = wid & 1;
  const int p  = blockIdx.x;                 // 512 blocks
  const int l  = (p & 7) * 64 + (p >> 3);
  const int m0 = (l & 15) * 256;
  const int n0 = (l >> 4) * 128;
  const int lr = lane & 15, lc = lane >> 4;

  const int ra   = tid >> 3;
  const int scol = ((tid & 7) ^ (ra & 7)) << 3;
  const unsigned short* pa = inter + (long)(m0 + ra) * IDIM + scol;
  unsigned short* lbase = (unsigned short*)As + wid * 512;

  const int rb  = tid >> 3;
  const int cb  = (tid & 7) << 3;
  const int swz = ((tid & 7) ^ (rb & 7)) << 3;
  const int sidx0 = rb * 64 + swz;
  const int sidx1 = (64 + rb) * 64 + swz;
  const int*   pd0 = dq + (long)(n0 + rb) * IDIM + cb;
  const int*   pd1 = pd0 + 64 * IDIM;
  const float* ps0 = dsc + (n0 + rb) * (IDIM / GRP);
  const float* ps1 = ps0 + 64 * (IDIM / GRP);

  int4 q[4];
  float sc[2];

#define DN_ISSUEA(KTA, WRP) do {                                              \
    const unsigned short* g_ = pa + (KTA) * 64;                               \
    unsigned short* l_ = lbase + (WRP) * 16384;                               \
    _Pragma("unroll")                                                         \
    for (int it = 0; it < 4; ++it)                                            \
      __builtin_amdgcn_global_load_lds(                                       \
          (const __attribute__((address_space(1))) unsigned int*)(g_ + it * 64 * IDIM), \
          (__attribute__((address_space(3))) unsigned int*)(l_ + it * 4096), 16, 0, 0); \
  } while (0)

#define DN_LOADB(KT) do { const int kk_ = (KT) << 6;                          \
    q[0] = *(const int4*)(pd0 + kk_); q[1] = *(const int4*)(pd0 + kk_ + 4);   \
    q[2] = *(const int4*)(pd1 + kk_); q[3] = *(const int4*)(pd1 + kk_ + 4);   \
    const int so_ = (KT) >> 1;                                                \
    sc[0] = ps0[so_]; sc[1] = ps1[so_]; } while (0)

#define DN_WRITEB(WRP) do {                                                   \
    unsigned short* B_ = (unsigned short*)Bs + (WRP) * 8192;                  \
    uint4 w_;                                                                 \
    w_.x = pk2((float)q[0].x * sc[0], (float)q[0].y * sc[0]);                 \
    w_.y = pk2((float)q[0].z * sc[0], (float)q[0].w * sc[0]);                 \
    w_.z = pk2((float)q[1].x * sc[0], (float)q[1].y * sc[0]);                 \
    w_.w = pk2((float)q[1].z * sc[0], (float)q[1].w * sc[0]);                 \
    *(uint4*)&B_[sidx0] = w_;                                                 \
    w_.x = pk2((float)q[2].x * sc[1], (float)q[2].y * sc[1]);                 \
    w_.y = pk2((float)q[2].z * sc[1], (float)q[2].w * sc[1]);                 \
    w_.z = pk2((float)q[3].x * sc[1], (float)q[3].y * sc[1]);                 \
    w_.w = pk2((float)q[3].z * sc[1], (float)q[3].w * sc[1]);                 \
    *(uint4*)&B_[sidx1] = w_;                                                 \
  } while (0)

  f32x4 acc[4][4];
  const f32x4 zero = {0.f, 0.f, 0.f, 0.f};
#pragma unroll
  for (int i = 0; i < 4; ++i)
#pragma unroll
    for (int j = 0; j < 4; ++j) acc[i][j] = zero;

  // prologue
  DN_LOADB(0);
  DN_ISSUEA(0, 0);
  DN_WRITEB(0);
  WAIT_VM0; WAIT_LGKM0;
  SBAR;
  SCHB;

  const int NKD = IDIM / 64;   // 224
#pragma unroll 1
  for (int kt = 0; kt < NKD; ++kt) {
    const int RD = kt & 1, WR = RD ^ 1;
    const int ktn = (kt + 1 < NKD) ? kt + 1 : kt;
    DN_LOADB(ktn);
    DN_ISSUEA(ktn, WR);
    SCHB;
    const unsigned short* Ab = (const unsigned short*)As + RD * 16384;
    const unsigned short* Bb = (const unsigned short*)Bs + RD * 8192;
    bf16x8 af[4], bfr[4];
#pragma unroll
    for (int ks = 0; ks < 2; ++ks) {
      const int soff = (((ks << 2) + lc) ^ (lr & 7)) << 3;
#pragma unroll
      for (int mi = 0; mi < 4; ++mi)
        af[mi] = *(const bf16x8*)&Ab[(wm * 64 + mi * 16 + lr) * 64 + soff];
#pragma unroll
      for (int ni = 0; ni < 4; ++ni)
        bfr[ni] = *(const bf16x8*)&Bb[(wn * 64 + ni * 16 + lr) * 64 + soff];
      SBAR; WAIT_LGKM0; SCHB;
      __builtin_amdgcn_s_setprio(1);
#pragma unroll
      for (int ni = 0; ni < 4; ++ni)
#pragma unroll
        for (int mi = 0; mi < 4; ++mi)
          acc[mi][ni] = __builtin_amdgcn_mfma_f32_16x16x32_bf16(af[mi], bfr[ni], acc[mi][ni], 0, 0, 0);
      __builtin_amdgcn_s_setprio(0);
      if (ks == 0) SBAR;
    }
    SCHB;
    WAIT_VM0;
    SCHB;
    DN_WRITEB(WR);
    WAIT_LGKM0;
    SBAR;
    SCHB;
  }

  const int r0 = m0 + wm * 64, c0 = n0 + wn * 64;
#pragma unroll
  for (int mi = 0; mi < 4; ++mi)
#pragma unroll
    for (int ni = 0; ni < 4; ++ni)
#pragma unroll
      for (int r = 0; r < 4; ++r) {
        int row = r0 + mi * 16 + lc * 4 + r;
        int col = c0 + ni * 16 + lr;
        out[(long)row * HDIM + col] = acc[mi][ni][r];
      }
#undef DN_ISSUEA
#undef DN_LOADB
#undef DN_WRITEB
}

extern "C" void kernel_launch(void* const* d_in, const int* in_sizes, int n_in,
                              void* d_out, int out_size, void* d_ws, size_t ws_size,
                              hipStream_t stream) {
  const float* x   = (const float*)d_in[0];
  const int*   gq  = (const int*)d_in[1];
  const float* gsc = (const float*)d_in[2];
  const int*   uq  = (const int*)d_in[3];
  const float* usc = (const float*)d_in[4];
  const int*   dq  = (const int*)d_in[5];
  const float* dsc = (const float*)d_in[6];
  float* out = (float*)d_out;

  // ws layout: xb [MTOK*HDIM] bf16 (32 MiB) | inter [MTOK*IDIM] bf16 (112 MiB)
  unsigned short* xb    = (unsigned short*)d_ws;
  unsigned short* inter = xb + (size_t)MTOK * HDIM;

  hipLaunchKernelGGL(cvt_x_kernel, dim3(2048), dim3(256), 0, stream, x, xb);
  hipLaunchKernelGGL(gateup_kernel, dim3(1792), dim3(512), 0, stream,
                     xb, gq, gsc, uq, usc, inter);
  hipLaunchKernelGGL(down_kernel, dim3(512), dim3(512), 0, stream,
                     inter, dq, dsc, out);
}